// Round 7
// baseline (32144.678 us; speedup 1.0000x reference)
//
#include <hip/hip_runtime.h>
#include <math.h>

#define NL   16
#define FD   2048
#define GD   256
#define TT   1024
#define BLK  256
#define FPT  8      // FD / BLK
#define NW   4      // BLK / 64 waves
#define EPSF 1e-7f

// ---- DPP wave-64 sum: canonical GCN one-sided tree, total valid in lane 63 ----
template<int CTRL, int RM>
__device__ __forceinline__ float dppadd(float v) {
    int t = __builtin_amdgcn_update_dpp(0, __float_as_int(v), CTRL, RM, 0xF, true);
    return v + __int_as_float(t);
}
__device__ __forceinline__ float wave_sum63(float v) {
    v = dppadd<0x111, 0xF>(v); // row_shr:1
    v = dppadd<0x112, 0xF>(v); // row_shr:2
    v = dppadd<0x114, 0xF>(v); // row_shr:4
    v = dppadd<0x118, 0xF>(v); // row_shr:8  -> lane 15/31/47/63 hold row sums
    v = dppadd<0x142, 0xA>(v); // row_bcast15 -> lane31 = r0+r1, lane63 = r2+r3
    v = dppadd<0x143, 0xC>(v); // row_bcast31 -> lane63 = total
    return v;
}

// block-wide 2-value sum; one barrier, parity-double-buffered slots
__device__ __forceinline__ void block_red2(float &a, float &b,
                                           float2 (&red2)[2][NW],
                                           int buf, int wv, int lane) {
    a = wave_sum63(a);
    b = wave_sum63(b);
    if (lane == 63) red2[buf][wv] = make_float2(a, b);
    __syncthreads();
    float sa = 0.f, sb = 0.f;
    #pragma unroll
    for (int w = 0; w < NW; ++w) { float2 r = red2[buf][w]; sa += r.x; sb += r.y; }
    a = sa; b = sb;
}

__global__ __launch_bounds__(BLK, 1)
void ipls_kernel(const float* __restrict__ Xg,  const float* __restrict__ Yg,
                 const float* __restrict__ mux0, const float* __restrict__ muy0,
                 const float* __restrict__ u0,   const float* __restrict__ Wz0,
                 const float* __restrict__ Cz0,  const float* __restrict__ tss0,
                 const float* __restrict__ bz0,  const float* __restrict__ P0,
                 const int*   __restrict__ n0p,  float* __restrict__ out)
{
    #pragma clang fp contract(off)   // match numpy: every mul and add rounds separately

    const int tid  = threadIdx.x;
    const int lane = tid & 63;
    const int wv   = tid >> 6;
    const int c0   = tid * FPT;      // this thread's 8 F-columns; 1 G-column (== tid)

    __shared__ __align__(16) float2 red2[2][NW];

    // ---- per-thread register state (all statically indexed) ----
    float x[FPT], mux[FPT];
    float Wz[NL][FPT], P[NL][FPT];
    float Czr[NL];
    float u_r[NL], tss_r[NL], bz_r[NL];   // redundant identical copies in every thread
    float y = 0.f, muy;

    #pragma unroll
    for (int j = 0; j < FPT; ++j) mux[j] = mux0[c0 + j];
    #pragma unroll
    for (int i = 0; i < NL; ++i) {
        #pragma unroll
        for (int j = 0; j < FPT; ++j) {
            Wz[i][j] = Wz0[i*FD + c0 + j];
            P[i][j]  = P0[i*FD + c0 + j];
        }
        Czr[i]   = Cz0[i*GD + tid];
        u_r[i]   = u0[i];
        tss_r[i] = tss0[i];
        bz_r[i]  = bz0[i];
    }
    muy = muy0[tid];

    int n = n0p[0];
    int rr = 0;   // reduction-round parity counter (reset each step; rounds/step is even)

    // prefetch row 0
    float4 nxa = *reinterpret_cast<const float4*>(Xg + c0);
    float4 nxb = *reinterpret_cast<const float4*>(Xg + c0 + 4);
    float  ny  = Yg[tid];

    for (int s = 0; s < TT; ++s) {
        float x0v[FPT] = {nxa.x, nxa.y, nxa.z, nxa.w, nxb.x, nxb.y, nxb.z, nxb.w};
        float y0v = ny;
        int sn = (s + 1 < TT) ? s + 1 : s;
        nxa = *reinterpret_cast<const float4*>(Xg + (size_t)sn*FD + c0);
        nxb = *reinterpret_cast<const float4*>(Xg + (size_t)sn*FD + c0 + 4);
        ny  = Yg[sn*GD + tid];

        // mean update: NEW n in numerator, divide by n+1 (IEEE div, no contraction)
        n += 1;
        float nf  = (float)n;
        float den = nf + 1.0f;
        #pragma unroll
        for (int j = 0; j < FPT; ++j) {
            float m  = mux[j] * nf;
            float s2 = m + x0v[j];
            mux[j] = s2 / den;
            x[j]   = x0v[j] - mux[j];
        }
        { float m = muy * nf; float s2 = m + y0v; muy = s2 / den; y = y0v - muy; }

        rr = 0;
        if (n <= 3) {
            // ---- burn-in: Wz += outer(u, x); tss += tz^2  (elementwise, 1 round/latent)
            #pragma unroll
            for (int i = 0; i < NL; ++i) {
                float uiv = u_r[i];
                float pd = 0.f, pn = 0.f;
                #pragma unroll
                for (int j = 0; j < FPT; ++j) {
                    float m = x[j] * uiv;
                    Wz[i][j] = Wz[i][j] + m;
                    pd = pd + Wz[i][j] * x[j];
                    pn = pn + Wz[i][j] * Wz[i][j];
                }
                block_red2(pd, pn, red2, rr & 1, wv, lane); ++rr;
                float tz = pd / (sqrtf(pn) + EPSF);
                float tq = tz * tz;
                tss_r[i] = tss_r[i] + tq;
            }
        } else {
            // ---- main: sequential deflation, elementwise-faithful inner loop ----
            #pragma unroll
            for (int i = 0; i < NL; ++i) {
                float ui   = u_r[i];
                float tssc = tss_r[i];
                float wz[FPT];
                float czv = 0.f, tz = 0.f, t = 0.f, tssn = 0.f, nc = 0.f;

                #pragma unroll
                for (int it = 0; it < 2; ++it) {
                    // x-side: wz = Wz[i] + x*ui  (elementwise, original x & Wz[i])
                    float pd = 0.f, pn = 0.f;
                    #pragma unroll
                    for (int j = 0; j < FPT; ++j) {
                        float m = x[j] * ui;
                        wz[j] = Wz[i][j] + m;
                        pd = pd + x[j] * wz[j];
                        pn = pn + wz[j] * wz[j];
                    }
                    block_red2(pd, pn, red2, rr & 1, wv, lane); ++rr;
                    tz = pd / (sqrtf(pn) + EPSF);
                    float tq = tz * tz;
                    tssn = tssc + tq;
                    t = tz / sqrtf(tssn);

                    // y-side: cz = Cz[i] + y*t  (elementwise, original y & Cz[i])
                    float m2 = y * t;
                    czv = Czr[i] + m2;
                    float pdy = y * czv;
                    float pnc = czv * czv;
                    block_red2(pdy, pnc, red2, rr & 1, wv, lane); ++rr;
                    nc = pnc;
                    ui = pdy / sqrtf(pnc);
                }

                // commit state (all threads compute identical scalars)
                u_r[i]   = ui;
                tss_r[i] = tssn;
                #pragma unroll
                for (int j = 0; j < FPT; ++j) Wz[i][j] = wz[j];
                Czr[i] = czv;

                float m4  = ui * tz;
                float bzn = bz_r[i] + m4;
                bz_r[i] = bzn;
                float b = bzn / sqrtf(tssn);

                // P_i = P + x*t;  x = x - t*P_i(new)
                #pragma unroll
                for (int j = 0; j < FPT; ++j) {
                    float m = x[j] * t;
                    P[i][j] = P[i][j] + m;
                    float m2 = t * P[i][j];
                    x[j] = x[j] - m2;
                }
                // y = y - (b*t) * (cz/sqrt(nc))
                float sqnc = sqrtf(nc);
                float Ci = czv / sqnc;
                float bt = b * t;
                float m5 = bt * Ci;
                y = y - m5;
            }
        }
    }

    // output: final P (16 x 2048)
    #pragma unroll
    for (int i = 0; i < NL; ++i) {
        #pragma unroll
        for (int j = 0; j < FPT; ++j)
            out[i*FD + c0 + j] = P[i][j];
    }
}

extern "C" void kernel_launch(void* const* d_in, const int* in_sizes, int n_in,
                              void* d_out, int out_size, void* d_ws, size_t ws_size,
                              hipStream_t stream) {
    const float* X    = (const float*)d_in[0];
    const float* Y    = (const float*)d_in[1];
    const float* mux  = (const float*)d_in[2];
    const float* muy  = (const float*)d_in[3];
    const float* u    = (const float*)d_in[4];
    const float* Wz   = (const float*)d_in[5];
    const float* Cz   = (const float*)d_in[6];
    const float* tss  = (const float*)d_in[7];
    const float* bz   = (const float*)d_in[8];
    const float* P    = (const float*)d_in[9];
    const int*   n0   = (const int*)d_in[10];

    ipls_kernel<<<1, BLK, 0, stream>>>(X, Y, mux, muy, u, Wz, Cz, tss, bz, P, n0,
                                       (float*)d_out);
}